// Round 6
// baseline (759.157 us; speedup 1.0000x reference)
//
#include <hip/hip_runtime.h>

// MultiHeadAttention with memory tokens + residual + LayerNorm.
// Inputs: float32 (mask int32).  OUTPUT: float32 (reference returns f32!).
// B=4, N=1024, D=1024, H=16, DK=64, M=64 memory tokens, NKV=1088.
//
// Intermediates bf16 (MFMA), f32 accumulation.  Layout:
//   d_out (16 MB f32) upper half doubles as Qb [4][1024][1024] bf16;
//   attention runs in-place over Qb; residual_ln writes f32 into d_out
//   front-to-back, only ever clobbering dead Qb slices.
//   ws (4,456,448 B): K_b [1088][1024] + Vt_b [16*64][1088] bf16, per batch;
//   PR (Wo-gemm out) aliases dead K_b.

typedef __bf16 bf16;
typedef __bf16 bf16x8 __attribute__((ext_vector_type(8)));
typedef __bf16 bf16x4 __attribute__((ext_vector_type(4)));
typedef float  f32x4  __attribute__((ext_vector_type(4)));

#define NSEQ 1024
#define NKV  1088   // 1024 + 64 memory tokens
#define DMODEL 1024

// ---------------------------------------------------------------------------
// C = A @ W.T + bias (NT gemm, f32 acc, bf16 out).  m92-verified pattern.
// A: [rows][1024] (bf16 if ABF else f32);  W: [1024][1024] f32;  bias: f32.
// VT=false: C[row][col] at row*1024+col.
// VT=true : V-transposed write C[(h*64+d)*NKV + j], h=col>>6, d=col&63, j=row.
template<bool ABF, bool VT>
__global__ __launch_bounds__(256) void gemm_nt(const void* __restrict__ Av,
        const float* __restrict__ W, const float* __restrict__ bias,
        bf16* __restrict__ C)
{
    __shared__ bf16 As[64][40];
    __shared__ bf16 Bs[64][40];
    const int t = threadIdx.x;
    const int lane = t & 63, w = t >> 6;
    const int wm = (w >> 1) * 32, wn = (w & 1) * 32;
    const int bm = blockIdx.y * 64, bn = blockIdx.x * 64;
    const int lr = t >> 2, lc = (t & 3) * 8;

    f32x4 acc[2][2] = {};

    for (int kt = 0; kt < DMODEL; kt += 32) {
        if (ABF) {
            *(bf16x8*)&As[lr][lc] =
                *(const bf16x8*)&((const bf16*)Av)[(size_t)(bm + lr) * DMODEL + kt + lc];
        } else {
            const float* ap = (const float*)Av + (size_t)(bm + lr) * DMODEL + kt + lc;
            f32x4 a0 = *(const f32x4*)ap, a1 = *(const f32x4*)(ap + 4);
            bf16x8 v;
            for (int i = 0; i < 4; i++) { v[i] = (bf16)a0[i]; v[4 + i] = (bf16)a1[i]; }
            *(bf16x8*)&As[lr][lc] = v;
        }
        {
            const float* wp = W + (size_t)(bn + lr) * DMODEL + kt + lc;
            f32x4 w0 = *(const f32x4*)wp, w1 = *(const f32x4*)(wp + 4);
            bf16x8 v;
            for (int i = 0; i < 4; i++) { v[i] = (bf16)w0[i]; v[4 + i] = (bf16)w1[i]; }
            *(bf16x8*)&Bs[lr][lc] = v;
        }
        __syncthreads();
        bf16x8 a0 = *(const bf16x8*)&As[wm +      (lane & 15)][(lane >> 4) * 8];
        bf16x8 a1 = *(const bf16x8*)&As[wm + 16 + (lane & 15)][(lane >> 4) * 8];
        bf16x8 b0 = *(const bf16x8*)&Bs[wn +      (lane & 15)][(lane >> 4) * 8];
        bf16x8 b1 = *(const bf16x8*)&Bs[wn + 16 + (lane & 15)][(lane >> 4) * 8];
        acc[0][0] = __builtin_amdgcn_mfma_f32_16x16x32_bf16(a0, b0, acc[0][0], 0, 0, 0);
        acc[0][1] = __builtin_amdgcn_mfma_f32_16x16x32_bf16(a0, b1, acc[0][1], 0, 0, 0);
        acc[1][0] = __builtin_amdgcn_mfma_f32_16x16x32_bf16(a1, b0, acc[1][0], 0, 0, 0);
        acc[1][1] = __builtin_amdgcn_mfma_f32_16x16x32_bf16(a1, b1, acc[1][1], 0, 0, 0);
        __syncthreads();
    }
    // C/D layout: row=(lane>>4)*4+r, col=lane&15  [m89-verified]
    for (int sm = 0; sm < 2; sm++)
        for (int sn = 0; sn < 2; sn++) {
            int col  = bn + wn + sn * 16 + (lane & 15);
            int row0 = bm + wm + sm * 16 + (lane >> 4) * 4;
            float bcol = bias[col];
            if (VT) {
                bf16x4 v;
                for (int r = 0; r < 4; r++) v[r] = (bf16)(acc[sm][sn][r] + bcol);
                size_t off = (size_t)col * NKV + row0;   // col = h*64+d, row0 = j
                *(bf16x4*)&C[off] = v;
            } else {
                for (int r = 0; r < 4; r++)
                    C[(size_t)(row0 + r) * DMODEL + col] = (bf16)(acc[sm][sn][r] + bcol);
            }
        }
}

// ---------------------------------------------------------------------------
// Memory tokens (one batch): K[1024+m][dcol] = m_k[m][dcol]*8 (sqrt(DK));
// Vt[(h*64+d)*NKV + 1024+m] = m_v[m][dcol]*8 (sqrt(M)), dcol = h*64+d.
__global__ void fill_mem(const float* __restrict__ mk, const float* __restrict__ mv,
                         bf16* __restrict__ K, bf16* __restrict__ Vt)
{
    int i = blockIdx.x * 256 + threadIdx.x;   // over M*D = 65536
    int m = i >> 10, dcol = i & 1023;
    K[(size_t)(NSEQ + m) * DMODEL + dcol] = (bf16)(mk[i] * 8.0f);
    Vt[(size_t)dcol * NKV + NSEQ + m]     = (bf16)(mv[i] * 8.0f);
}

// ---------------------------------------------------------------------------
// Two-pass MFMA attention (one batch), 16 q-rows per block, one h per blockIdx.y.
// Pass1: S = Q K^T * scale (bf16, LDS).  Softmax in-place (masked, unnormalized
// p; 1/sum folded into epilogue).  Pass2: O = P V via Vt tiles.
// Q and O alias (in-place): each block reads/writes only its own
// [q0:q0+16][h*64:+64] region.
__global__ __launch_bounds__(256) void attention(const bf16* Q,
        const bf16* __restrict__ K, const bf16* __restrict__ Vt,
        const int* __restrict__ mask, bf16* O)
{
    __shared__ bf16  sS[16][NKV + 8];   // 35.1 KB: scaled scores, then p
    __shared__ bf16  sT[64][72];        // K tile / Vt tile staging
    __shared__ float sInv[16];
    const int t = threadIdx.x, lane = t & 63, w = t >> 6;
    const int h = blockIdx.y;
    const int q0 = blockIdx.x * 16;
    const int sr = t >> 2, sc = (t & 3) * 16;

    // Q a-frags in registers for all of pass 1: A[m=lane&15][k=(lane>>4)*8+j]
    const size_t qbase = (size_t)(q0 + (lane & 15)) * DMODEL + h * 64 + (lane >> 4) * 8;
    bf16x8 qa0 = *(const bf16x8*)&Q[qbase];
    bf16x8 qa1 = *(const bf16x8*)&Q[qbase + 32];

    // ---- pass 1: scores ----
    for (int jt = 0; jt < 17; jt++) {
        const bf16* kp = K + (size_t)(jt * 64 + sr) * DMODEL + h * 64 + sc;
        *(bf16x8*)&sT[sr][sc]     = *(const bf16x8*)kp;
        *(bf16x8*)&sT[sr][sc + 8] = *(const bf16x8*)(kp + 8);
        __syncthreads();
        bf16x8 b0 = *(const bf16x8*)&sT[w * 16 + (lane & 15)][(lane >> 4) * 8];
        bf16x8 b1 = *(const bf16x8*)&sT[w * 16 + (lane & 15)][32 + (lane >> 4) * 8];
        f32x4 s = {};
        s = __builtin_amdgcn_mfma_f32_16x16x32_bf16(qa0, b0, s, 0, 0, 0);
        s = __builtin_amdgcn_mfma_f32_16x16x32_bf16(qa1, b1, s, 0, 0, 0);
        int col = jt * 64 + w * 16 + (lane & 15);
        int rb = (lane >> 4) * 4;
        sS[rb + 0][col] = (bf16)(s[0] * 0.125f);   // 1/sqrt(DK)
        sS[rb + 1][col] = (bf16)(s[1] * 0.125f);
        sS[rb + 2][col] = (bf16)(s[2] * 0.125f);
        sS[rb + 3][col] = (bf16)(s[3] * 0.125f);
        __syncthreads();
    }

    // ---- softmax (row r handled by 16 lanes, 68 cols each) ----
    {
        const int r = t >> 4, jl = t & 15;
        float mx = -3.0e38f;
        for (int i = 0; i < 68; i++) {
            int j = jl + 16 * i;
            float sv = (float)sS[r][j];
            bool msk = (j < NSEQ) && (mask[j] != 0);   // mask==1 -> excluded
            sv = msk ? -3.0e38f : sv;
            sS[r][j] = (bf16)sv;
            mx = fmaxf(mx, sv);
        }
        for (int o = 8; o; o >>= 1) mx = fmaxf(mx, __shfl_xor(mx, o, 16));
        float sum = 0.f;
        for (int i = 0; i < 68; i++) {
            int j = jl + 16 * i;
            float p = __expf((float)sS[r][j] - mx);
            sum += p;
            sS[r][j] = (bf16)p;   // unnormalized
        }
        for (int o = 8; o; o >>= 1) sum += __shfl_xor(sum, o, 16);
        if (jl == 0) sInv[r] = 1.0f / sum;
    }
    __syncthreads();

    // ---- pass 2: O = P V ----
    f32x4 oacc = {};
    for (int jt = 0; jt < 17; jt++) {
        const bf16* vp = Vt + (size_t)(h * 64 + sr) * NKV + jt * 64 + sc;
        *(bf16x8*)&sT[sr][sc]     = *(const bf16x8*)vp;
        *(bf16x8*)&sT[sr][sc + 8] = *(const bf16x8*)(vp + 8);
        __syncthreads();
        for (int kk = 0; kk < 2; kk++) {
            bf16x8 af = *(const bf16x8*)&sS[lane & 15][jt * 64 + kk * 32 + (lane >> 4) * 8];
            bf16x8 bv = *(const bf16x8*)&sT[w * 16 + (lane & 15)][kk * 32 + (lane >> 4) * 8];
            oacc = __builtin_amdgcn_mfma_f32_16x16x32_bf16(af, bv, oacc, 0, 0, 0);
        }
        __syncthreads();
    }
    // epilogue: O[q0+row][h*64 + w*16 + (lane&15)], normalize by 1/sum
    {
        int col = w * 16 + (lane & 15);
        for (int r = 0; r < 4; r++) {
            int row = (lane >> 4) * 4 + r;
            float v = oacc[r] * sInv[row];
            O[(size_t)(q0 + row) * DMODEL + h * 64 + col] = (bf16)v;
        }
    }
}

// ---------------------------------------------------------------------------
// out = LayerNorm(X + Y) * gamma + beta, one row (1024) per block.
// X (residual input) f32, Y (Wo-gemm out) bf16, gamma/beta f32, OUT F32.
__global__ __launch_bounds__(256) void residual_ln(const float* __restrict__ X,
        const bf16* __restrict__ Y, const float* __restrict__ gamma,
        const float* __restrict__ beta, float* __restrict__ out)
{
    __shared__ float red[8];
    int row = blockIdx.x, t = threadIdx.x;
    size_t base = (size_t)row * DMODEL + t * 4;
    f32x4  xv = *(const f32x4*)&X[base];
    bf16x4 yv = *(const bf16x4*)&Y[base];
    float s[4], sum = 0.f, sq = 0.f;
    for (int i = 0; i < 4; i++) {
        s[i] = xv[i] + (float)yv[i];
        sum += s[i]; sq += s[i] * s[i];
    }
    for (int o = 32; o; o >>= 1) { sum += __shfl_xor(sum, o, 64); sq += __shfl_xor(sq, o, 64); }
    if ((t & 63) == 0) { red[t >> 6] = sum; red[4 + (t >> 6)] = sq; }
    __syncthreads();
    sum = red[0] + red[1] + red[2] + red[3];
    sq  = red[4] + red[5] + red[6] + red[7];
    float mean = sum * (1.0f / DMODEL);
    float var  = sq  * (1.0f / DMODEL) - mean * mean;   // population var (jnp.var)
    float rstd = rsqrtf(var + 1e-5f);
    f32x4 gv = *(const f32x4*)&gamma[t * 4];
    f32x4 bv = *(const f32x4*)&beta[t * 4];
    f32x4 ov;
    for (int i = 0; i < 4; i++)
        ov[i] = (s[i] - mean) * rstd * gv[i] + bv[i];
    *(f32x4*)&out[base] = ov;
}

// ---------------------------------------------------------------------------
extern "C" void kernel_launch(void* const* d_in, const int* in_sizes, int n_in,
                              void* d_out, int out_size, void* d_ws, size_t ws_size,
                              hipStream_t stream)
{
    const float* queries = (const float*)d_in[0];
    const float* keys    = (const float*)d_in[1];
    const float* values  = (const float*)d_in[2];
    const int*   amask   = (const int*)d_in[3];
    const float* Wq = (const float*)d_in[4];  const float* bq = (const float*)d_in[5];
    const float* Wk = (const float*)d_in[6];  const float* bk = (const float*)d_in[7];
    const float* Wv = (const float*)d_in[8];  const float* bv = (const float*)d_in[9];
    const float* Wo = (const float*)d_in[10]; const float* bo = (const float*)d_in[11];
    const float* mk = (const float*)d_in[12]; const float* mv = (const float*)d_in[13];
    const float* gamma = (const float*)d_in[14]; const float* beta = (const float*)d_in[15];
    float* out = (float*)d_out;   // f32 output (reference returns float32)

    // Qb (bf16, 8 MB) lives in the UPPER half of the 16 MB f32 d_out.
    // residual_ln(b) writes f32 bytes [4b MB, 4b+4 MB): only clobbers Qb
    // slices that are already consumed (slice b is used in phases <= b).
    bf16* Qb = (bf16*)(out + (size_t)2 * 1024 * 1024);   // byte offset 8 MB
    bf16* Kb = (bf16*)d_ws;                         // [1088][1024]  bf16
    bf16* Vt = Kb + (size_t)NKV * DMODEL;           // [16*64][1088] bf16
    bf16* PR = Kb;                                  // [1024][1024], aliases dead K_b

    const size_t SB = (size_t)NSEQ * DMODEL;        // per-batch slice (1M elems)
    dim3 gb(256);

    // Q projection for all batches -> Qb (upper half of d_out)
    gemm_nt<false, false><<<dim3(16, 64), gb, 0, stream>>>(queries, Wq, bq, Qb);

    for (int b = 0; b < 4; b++) {
        gemm_nt<false, false><<<dim3(16, 16), gb, 0, stream>>>(keys   + b * SB, Wk, bk, Kb);
        gemm_nt<false, true ><<<dim3(16, 16), gb, 0, stream>>>(values + b * SB, Wv, bv, Vt);
        fill_mem<<<dim3(256), gb, 0, stream>>>(mk, mv, Kb, Vt);
        attention<<<dim3(64, 16), gb, 0, stream>>>(Qb + b * SB, Kb, Vt,
                                                   amask + b * NSEQ, Qb + b * SB);
        gemm_nt<true, false><<<dim3(16, 16), gb, 0, stream>>>(Qb + b * SB, Wo, bo, PR);
        residual_ln<<<dim3(1024), gb, 0, stream>>>(queries + b * SB, PR,
                                                   gamma, beta, out + b * SB);
    }
}

// Round 7
// 322.997 us; speedup vs baseline: 2.3504x; 2.3504x over previous
//
#include <hip/hip_runtime.h>

// MultiHeadAttention with memory tokens + residual + LayerNorm.
// Inputs f32 (mask int32), OUTPUT f32.  B=4, N=1024, D=1024, H=16, DK=64,
// M=64, NKV=1088.  Intermediates bf16 (MFMA), f32 accumulation.
//
// R7: flash attention (64 q-rows/block, online softmax) + fully batched
// pipeline when ws_size allows (17.8 MB), else proven per-batch fallback.
// d_out (16MB f32): upper half doubles as Qb [4][1024][1024] bf16.

typedef __bf16 bf16;
typedef __bf16 bf16x8 __attribute__((ext_vector_type(8)));
typedef __bf16 bf16x4 __attribute__((ext_vector_type(4)));
typedef float  f32x4  __attribute__((ext_vector_type(4)));

#define NSEQ 1024
#define NKV  1088
#define DMODEL 1024

// ---------------------------------------------------------------------------
// C = A @ W.T + bias (NT gemm, f32 acc, bf16 out).  m92-verified pattern.
// A: [rows][1024] (bf16 if ABF else f32); W f32; bias f32.
// VT=false: off = (row>>10)*osK + (row&1023)*1024 + col.
// VT=true : Vt[((row>>10)*16 + col>>6)*64 + (col&63)][row&1023], stride NKV.
template<bool ABF, bool VT>
__global__ __launch_bounds__(256) void gemm_nt(const void* __restrict__ Av,
        const float* __restrict__ W, const float* __restrict__ bias,
        bf16* __restrict__ C, int osK)
{
    __shared__ bf16 As[64][40];
    __shared__ bf16 Bs[64][40];
    const int t = threadIdx.x;
    const int lane = t & 63, w = t >> 6;
    const int wm = (w >> 1) * 32, wn = (w & 1) * 32;
    const int bm = blockIdx.y * 64, bn = blockIdx.x * 64;
    const int lr = t >> 2, lc = (t & 3) * 8;

    f32x4 acc[2][2] = {};

    for (int kt = 0; kt < DMODEL; kt += 32) {
        if (ABF) {
            *(bf16x8*)&As[lr][lc] =
                *(const bf16x8*)&((const bf16*)Av)[(size_t)(bm + lr) * DMODEL + kt + lc];
        } else {
            const float* ap = (const float*)Av + (size_t)(bm + lr) * DMODEL + kt + lc;
            f32x4 a0 = *(const f32x4*)ap, a1 = *(const f32x4*)(ap + 4);
            bf16x8 v;
            for (int i = 0; i < 4; i++) { v[i] = (bf16)a0[i]; v[4 + i] = (bf16)a1[i]; }
            *(bf16x8*)&As[lr][lc] = v;
        }
        {
            const float* wp = W + (size_t)(bn + lr) * DMODEL + kt + lc;
            f32x4 w0 = *(const f32x4*)wp, w1 = *(const f32x4*)(wp + 4);
            bf16x8 v;
            for (int i = 0; i < 4; i++) { v[i] = (bf16)w0[i]; v[4 + i] = (bf16)w1[i]; }
            *(bf16x8*)&Bs[lr][lc] = v;
        }
        __syncthreads();
        bf16x8 a0 = *(const bf16x8*)&As[wm +      (lane & 15)][(lane >> 4) * 8];
        bf16x8 a1 = *(const bf16x8*)&As[wm + 16 + (lane & 15)][(lane >> 4) * 8];
        bf16x8 b0 = *(const bf16x8*)&Bs[wn +      (lane & 15)][(lane >> 4) * 8];
        bf16x8 b1 = *(const bf16x8*)&Bs[wn + 16 + (lane & 15)][(lane >> 4) * 8];
        acc[0][0] = __builtin_amdgcn_mfma_f32_16x16x32_bf16(a0, b0, acc[0][0], 0, 0, 0);
        acc[0][1] = __builtin_amdgcn_mfma_f32_16x16x32_bf16(a0, b1, acc[0][1], 0, 0, 0);
        acc[1][0] = __builtin_amdgcn_mfma_f32_16x16x32_bf16(a1, b0, acc[1][0], 0, 0, 0);
        acc[1][1] = __builtin_amdgcn_mfma_f32_16x16x32_bf16(a1, b1, acc[1][1], 0, 0, 0);
        __syncthreads();
    }
    for (int sm = 0; sm < 2; sm++)
        for (int sn = 0; sn < 2; sn++) {
            int col  = bn + wn + sn * 16 + (lane & 15);
            int row0 = bm + wm + sm * 16 + (lane >> 4) * 4;
            float bcol = bias[col];
            if (VT) {
                bf16x4 v;
                for (int r = 0; r < 4; r++) v[r] = (bf16)(acc[sm][sn][r] + bcol);
                size_t off = ((size_t)((row0 >> 10) * 16 + (col >> 6)) * 64 + (col & 63))
                           * NKV + (row0 & 1023);
                *(bf16x4*)&C[off] = v;
            } else {
                for (int r = 0; r < 4; r++) {
                    int row = row0 + r;
                    size_t off = (size_t)(row >> 10) * osK
                               + (size_t)(row & 1023) * DMODEL + col;
                    C[off] = (bf16)(acc[sm][sn][r] + bcol);
                }
            }
        }
}

// ---------------------------------------------------------------------------
// Memory tokens: i over nb*M*D.  K[b][1024+m][dcol] = m_k*8;  Vt[...] = m_v*8.
__global__ void fill_mem(const float* __restrict__ mk, const float* __restrict__ mv,
                         bf16* __restrict__ K, bf16* __restrict__ Vt)
{
    int i = blockIdx.x * 256 + threadIdx.x;
    int b = i >> 16, md = i & 65535;
    int m = md >> 10, dcol = md & 1023;
    K[(size_t)b * (NKV * DMODEL) + (size_t)(NSEQ + m) * DMODEL + dcol]
        = (bf16)(mk[md] * 8.0f);
    Vt[((size_t)b * 1024 + dcol) * NKV + NSEQ + m] = (bf16)(mv[md] * 8.0f);
}

// ---------------------------------------------------------------------------
// Flash attention: grid (NSEQ/64, nb*16).  Block = 4 waves; wave w owns
// q-rows q0+w*16..+16, full 64-dim head output, online softmax in regs.
// P transposed C-layout -> A-layout via per-wave LDS round-trip (m120).
// Q/O alias in-place; blocks touch disjoint [rows][head-cols] regions.
__global__ __launch_bounds__(256) void attn_flash(const bf16* Q,
        const bf16* __restrict__ K, const bf16* __restrict__ Vt,
        const int* __restrict__ mask, bf16* O)
{
    __shared__ bf16  sK[64][72];      // K tile [j][d]
    __shared__ bf16  sV[64][72];      // V tile [d][j]
    __shared__ bf16  sP[4][16][72];   // per-wave P [row][j]
    __shared__ float sM[NKV];         // additive mask
    const int t = threadIdx.x, lane = t & 63, w = t >> 6;
    const int bh = blockIdx.y, b = bh >> 4, h = bh & 15;
    const int q0 = blockIdx.x * 64;
    const int sr = t >> 2, sc = (t & 3) * 16;
    const int qi = lane & 15, qq = lane >> 4;

    for (int j = t; j < NKV; j += 256)
        sM[j] = (j < NSEQ && mask[b * NSEQ + j] != 0) ? -3.0e38f : 0.0f;

    // Q a-frags: A[m=qi][k=qq*8+jj], chunks k0/k32
    const size_t qbase = (size_t)(b * NSEQ + q0 + w * 16 + qi) * DMODEL
                       + h * 64 + qq * 8;
    bf16x8 qa0 = *(const bf16x8*)&Q[qbase];
    bf16x8 qa1 = *(const bf16x8*)&Q[qbase + 32];

    float m_i[4], l_i[4];
    f32x4 oacc[4] = {};
    for (int r = 0; r < 4; r++) { m_i[r] = -3.0e38f; l_i[r] = 0.f; }

    for (int jt = 0; jt < 17; jt++) {
        const int j0 = jt * 64;
        const bf16* kp = K + (size_t)(b * NKV + j0 + sr) * DMODEL + h * 64 + sc;
        *(bf16x8*)&sK[sr][sc]     = *(const bf16x8*)kp;
        *(bf16x8*)&sK[sr][sc + 8] = *(const bf16x8*)(kp + 8);
        const bf16* vp = Vt + ((size_t)bh * 64 + sr) * NKV + j0 + sc;
        *(bf16x8*)&sV[sr][sc]     = *(const bf16x8*)vp;
        *(bf16x8*)&sV[sr][sc + 8] = *(const bf16x8*)(vp + 8);
        __syncthreads();

        // S tile: group g -> cols j0+g*16+qi; rows w*16+qq*4+r (C-layout)
        f32x4 s[4];
        for (int g = 0; g < 4; g++) {
            bf16x8 b0 = *(const bf16x8*)&sK[g * 16 + qi][qq * 8];
            bf16x8 b1 = *(const bf16x8*)&sK[g * 16 + qi][32 + qq * 8];
            f32x4 a = {};
            a = __builtin_amdgcn_mfma_f32_16x16x32_bf16(qa0, b0, a, 0, 0, 0);
            a = __builtin_amdgcn_mfma_f32_16x16x32_bf16(qa1, b1, a, 0, 0, 0);
            float msk = sM[j0 + g * 16 + qi];
            for (int r = 0; r < 4; r++) s[g][r] = a[r] * 0.125f + msk;
        }
        // online softmax (row stats across the quad's 16 lanes)
        float alpha[4];
        for (int r = 0; r < 4; r++) {
            float rm = fmaxf(fmaxf(s[0][r], s[1][r]), fmaxf(s[2][r], s[3][r]));
            for (int o = 1; o < 16; o <<= 1) rm = fmaxf(rm, __shfl_xor(rm, o, 64));
            float mnew = fmaxf(m_i[r], rm);
            alpha[r] = __expf(m_i[r] - mnew);
            m_i[r] = mnew;
            float rs = 0.f;
            for (int g = 0; g < 4; g++) {
                float p = __expf(s[g][r] - mnew);
                s[g][r] = p;
                rs += p;
            }
            for (int o = 1; o < 16; o <<= 1) rs += __shfl_xor(rs, o, 64);
            l_i[r] = l_i[r] * alpha[r] + rs;
        }
        // P -> per-wave LDS (C-layout write), rescale O
        for (int g = 0; g < 4; g++)
            for (int r = 0; r < 4; r++) {
                sP[w][qq * 4 + r][g * 16 + qi] = (bf16)s[g][r];
                oacc[g][r] *= alpha[r];
            }
        // A-layout read-back (within-wave dep; compiler orders via lgkmcnt)
        bf16x8 af0 = *(const bf16x8*)&sP[w][qi][qq * 8];
        bf16x8 af1 = *(const bf16x8*)&sP[w][qi][32 + qq * 8];
        for (int g = 0; g < 4; g++) {
            bf16x8 v0 = *(const bf16x8*)&sV[g * 16 + qi][qq * 8];
            bf16x8 v1 = *(const bf16x8*)&sV[g * 16 + qi][32 + qq * 8];
            oacc[g] = __builtin_amdgcn_mfma_f32_16x16x32_bf16(af0, v0, oacc[g], 0, 0, 0);
            oacc[g] = __builtin_amdgcn_mfma_f32_16x16x32_bf16(af1, v1, oacc[g], 0, 0, 0);
        }
        __syncthreads();
    }
    for (int g = 0; g < 4; g++)
        for (int r = 0; r < 4; r++) {
            int row = q0 + w * 16 + qq * 4 + r;
            int col = h * 64 + g * 16 + qi;
            O[(size_t)(b * NSEQ + row) * DMODEL + col] = (bf16)(oacc[g][r] / l_i[r]);
        }
}

// ---------------------------------------------------------------------------
// out = LayerNorm(X + Y) * gamma + beta, one row per block.  X f32, Y bf16.
__global__ __launch_bounds__(256) void residual_ln(const float* __restrict__ X,
        const bf16* __restrict__ Y, const float* __restrict__ gamma,
        const float* __restrict__ beta, float* __restrict__ out)
{
    __shared__ float red[8];
    int row = blockIdx.x, t = threadIdx.x;
    size_t base = (size_t)row * DMODEL + t * 4;
    f32x4  xv = *(const f32x4*)&X[base];
    bf16x4 yv = *(const bf16x4*)&Y[base];
    float s[4], sum = 0.f, sq = 0.f;
    for (int i = 0; i < 4; i++) {
        s[i] = xv[i] + (float)yv[i];
        sum += s[i]; sq += s[i] * s[i];
    }
    for (int o = 32; o; o >>= 1) { sum += __shfl_xor(sum, o, 64); sq += __shfl_xor(sq, o, 64); }
    if ((t & 63) == 0) { red[t >> 6] = sum; red[4 + (t >> 6)] = sq; }
    __syncthreads();
    sum = red[0] + red[1] + red[2] + red[3];
    sq  = red[4] + red[5] + red[6] + red[7];
    float mean = sum * (1.0f / DMODEL);
    float var  = sq  * (1.0f / DMODEL) - mean * mean;
    float rstd = rsqrtf(var + 1e-5f);
    f32x4 gv = *(const f32x4*)&gamma[t * 4];
    f32x4 bv = *(const f32x4*)&beta[t * 4];
    f32x4 ov;
    for (int i = 0; i < 4; i++)
        ov[i] = (s[i] - mean) * rstd * gv[i] + bv[i];
    *(f32x4*)&out[base] = ov;
}

// ---------------------------------------------------------------------------
extern "C" void kernel_launch(void* const* d_in, const int* in_sizes, int n_in,
                              void* d_out, int out_size, void* d_ws, size_t ws_size,
                              hipStream_t stream)
{
    const float* queries = (const float*)d_in[0];
    const float* keys    = (const float*)d_in[1];
    const float* values  = (const float*)d_in[2];
    const int*   amask   = (const int*)d_in[3];
    const float* Wq = (const float*)d_in[4];  const float* bq = (const float*)d_in[5];
    const float* Wk = (const float*)d_in[6];  const float* bk = (const float*)d_in[7];
    const float* Wv = (const float*)d_in[8];  const float* bv = (const float*)d_in[9];
    const float* Wo = (const float*)d_in[10]; const float* bo = (const float*)d_in[11];
    const float* mk = (const float*)d_in[12]; const float* mv = (const float*)d_in[13];
    const float* gamma = (const float*)d_in[14]; const float* beta = (const float*)d_in[15];
    float* out = (float*)d_out;

    bf16* Qb = (bf16*)(out + (size_t)2 * 1024 * 1024);   // d_out upper 8 MB
    const size_t SB  = (size_t)NSEQ * DMODEL;
    const size_t KVB = (size_t)NKV * DMODEL;
    dim3 gb(256);

    if (ws_size >= (size_t)2 * 4 * KVB * sizeof(bf16)) {
        // ---------- fully batched path (ws >= 17,825,792 B) ----------
        bf16* Kb = (bf16*)d_ws;            // [4][1088][1024]
        bf16* Vt = Kb + 4 * KVB;           // [4*16*64][1088]
        bf16* PR = Kb;                     // [4096][1024] aliases dead Kb

        gemm_nt<false, false><<<dim3(16, 64), gb, 0, stream>>>(queries, Wq, bq, Qb, (int)SB);
        gemm_nt<false, false><<<dim3(16, 64), gb, 0, stream>>>(keys,    Wk, bk, Kb, (int)KVB);
        gemm_nt<false, true ><<<dim3(16, 64), gb, 0, stream>>>(values,  Wv, bv, Vt, 0);
        fill_mem<<<dim3(1024), gb, 0, stream>>>(mk, mv, Kb, Vt);
        attn_flash<<<dim3(16, 64), gb, 0, stream>>>(Qb, Kb, Vt, amask, Qb);
        gemm_nt<true, false><<<dim3(16, 64), gb, 0, stream>>>(Qb, Wo, bo, PR, (int)SB);
        residual_ln<<<dim3(4096), gb, 0, stream>>>(queries, PR, gamma, beta, out);
    } else {
        // ---------- per-batch fallback (ws >= 4,456,448 B) ----------
        bf16* Kb = (bf16*)d_ws;            // [1088][1024]
        bf16* Vt = Kb + KVB;               // [16*64][1088]
        bf16* PR = Kb;

        gemm_nt<false, false><<<dim3(16, 64), gb, 0, stream>>>(queries, Wq, bq, Qb, (int)SB);
        for (int b = 0; b < 4; b++) {
            gemm_nt<false, false><<<dim3(16, 16), gb, 0, stream>>>(keys   + b * SB, Wk, bk, Kb, 0);
            gemm_nt<false, true ><<<dim3(16, 16), gb, 0, stream>>>(values + b * SB, Wv, bv, Vt, 0);
            fill_mem<<<dim3(256), gb, 0, stream>>>(mk, mv, Kb, Vt);
            attn_flash<<<dim3(16, 16), gb, 0, stream>>>(Qb + b * SB, Kb, Vt,
                                                        amask + b * NSEQ, Qb + b * SB);
            gemm_nt<true, false><<<dim3(16, 16), gb, 0, stream>>>(Qb + b * SB, Wo, bo, PR, 0);
            residual_ln<<<dim3(1024), gb, 0, stream>>>(queries + b * SB, PR,
                                                       gamma, beta, out + b * SB);
        }
    }
}

// Round 8
// 302.180 us; speedup vs baseline: 2.5123x; 1.0689x over previous
//
#include <hip/hip_runtime.h>

// MultiHeadAttention with memory tokens + residual + LayerNorm.
// Inputs f32 (mask int32), OUTPUT f32.  B=4, N=1024, D=1024, H=16, DK=64,
// M=64, NKV=1088.  Intermediates bf16 (MFMA), f32 accumulation.
//
// R8: 128x128-tile GEMM (QKV merged into one gridDim.z=3 dispatch) + flash
// attention.  d_out (16MB f32): upper half doubles as Qb [4][1024][1024] bf16.

typedef __bf16 bf16;
typedef __bf16 bf16x8 __attribute__((ext_vector_type(8)));
typedef __bf16 bf16x4 __attribute__((ext_vector_type(4)));
typedef float  f32x4  __attribute__((ext_vector_type(4)));

#define NSEQ 1024
#define NKV  1088
#define DMODEL 1024

struct GemmArgs {
    const void* A;        // [M][1024] f32 (or bf16 if ABF)
    const float* W;       // [1024][1024] f32
    const float* bias;    // [1024] f32
    bf16* C;
    int osK;              // batch stride for multi-batch row remap (VT=0)
    int vt;               // 1: V-transposed epilogue
};

// ---------------------------------------------------------------------------
// C = A @ W.T + bias.  128x128 tile, BK=32, 4 waves (2x2), 4x4 16x16 frags.
// grid: (N/128, M/128, nz); z selects the arg set.
// vt=0: off = (row>>10)*osK + (row&1023)*1024 + col
// vt=1: Vt[((row>>10)*16 + col>>6)*64 + (col&63)][row&1023], stride NKV
template<bool ABF>
__global__ __launch_bounds__(256, 2) void gemm128(GemmArgs g0, GemmArgs g1, GemmArgs g2)
{
    const GemmArgs g = (blockIdx.z == 0) ? g0 : (blockIdx.z == 1) ? g1 : g2;
    __shared__ bf16 As[128][44];   // pad 44: frag reads ~2-way, writes <=4-way
    __shared__ bf16 Bs[128][44];
    const int t = threadIdx.x;
    const int lane = t & 63, w = t >> 6;
    const int qi = lane & 15, qq = lane >> 4;
    const int wrow = (w >> 1) * 64, wcol = (w & 1) * 64;
    const int bm = blockIdx.y * 128, bn = blockIdx.x * 128;
    const int sr = t >> 1, sc = (t & 1) * 16;   // staging: 2 thr/row, 16 elems

    f32x4 acc[4][4] = {};

    for (int kt = 0; kt < DMODEL; kt += 32) {
        if (ABF) {
            const bf16* ap = (const bf16*)g.A + (size_t)(bm + sr) * DMODEL + kt + sc;
            *(bf16x8*)&As[sr][sc]     = *(const bf16x8*)ap;
            *(bf16x8*)&As[sr][sc + 8] = *(const bf16x8*)(ap + 8);
        } else {
            const float* ap = (const float*)g.A + (size_t)(bm + sr) * DMODEL + kt + sc;
            f32x4 a0 = *(const f32x4*)ap,       a1 = *(const f32x4*)(ap + 4);
            f32x4 a2 = *(const f32x4*)(ap + 8), a3 = *(const f32x4*)(ap + 12);
            bf16x8 v0, v1;
            for (int i = 0; i < 4; i++) {
                v0[i] = (bf16)a0[i]; v0[4 + i] = (bf16)a1[i];
                v1[i] = (bf16)a2[i]; v1[4 + i] = (bf16)a3[i];
            }
            *(bf16x8*)&As[sr][sc]     = v0;
            *(bf16x8*)&As[sr][sc + 8] = v1;
        }
        {
            const float* wp = g.W + (size_t)(bn + sr) * DMODEL + kt + sc;
            f32x4 w0 = *(const f32x4*)wp,       w1 = *(const f32x4*)(wp + 4);
            f32x4 w2 = *(const f32x4*)(wp + 8), w3 = *(const f32x4*)(wp + 12);
            bf16x8 v0, v1;
            for (int i = 0; i < 4; i++) {
                v0[i] = (bf16)w0[i]; v0[4 + i] = (bf16)w1[i];
                v1[i] = (bf16)w2[i]; v1[4 + i] = (bf16)w3[i];
            }
            *(bf16x8*)&Bs[sr][sc]     = v0;
            *(bf16x8*)&Bs[sr][sc + 8] = v1;
        }
        __syncthreads();
        bf16x8 a[4], b[4];
        for (int i = 0; i < 4; i++)
            a[i] = *(const bf16x8*)&As[wrow + i * 16 + qi][qq * 8];
        for (int j = 0; j < 4; j++)
            b[j] = *(const bf16x8*)&Bs[wcol + j * 16 + qi][qq * 8];
        for (int i = 0; i < 4; i++)
            for (int j = 0; j < 4; j++)
                acc[i][j] = __builtin_amdgcn_mfma_f32_16x16x32_bf16(a[i], b[j], acc[i][j], 0, 0, 0);
        __syncthreads();
    }
    // epilogue; C/D layout row=qq*4+r, col=qi  [m89-verified]
    for (int i = 0; i < 4; i++)
        for (int j = 0; j < 4; j++) {
            int row0 = bm + wrow + i * 16 + qq * 4;
            int col  = bn + wcol + j * 16 + qi;
            float bcol = g.bias[col];
            if (g.vt) {
                bf16x4 v;
                for (int r = 0; r < 4; r++) v[r] = (bf16)(acc[i][j][r] + bcol);
                size_t off = ((size_t)((row0 >> 10) * 16 + (col >> 6)) * 64 + (col & 63))
                           * NKV + (row0 & 1023);
                *(bf16x4*)&g.C[off] = v;
            } else {
                for (int r = 0; r < 4; r++) {
                    int row = row0 + r;
                    size_t off = (size_t)(row >> 10) * g.osK
                               + (size_t)(row & 1023) * DMODEL + col;
                    g.C[off] = (bf16)(acc[i][j][r] + bcol);
                }
            }
        }
}

// ---------------------------------------------------------------------------
// Memory tokens: i over nb*M*D.  K[b][1024+m][dcol] = m_k*8;  Vt[...] = m_v*8.
__global__ void fill_mem(const float* __restrict__ mk, const float* __restrict__ mv,
                         bf16* __restrict__ K, bf16* __restrict__ Vt)
{
    int i = blockIdx.x * 256 + threadIdx.x;
    int b = i >> 16, md = i & 65535;
    int m = md >> 10, dcol = md & 1023;
    K[(size_t)b * (NKV * DMODEL) + (size_t)(NSEQ + m) * DMODEL + dcol]
        = (bf16)(mk[md] * 8.0f);
    Vt[((size_t)b * 1024 + dcol) * NKV + NSEQ + m] = (bf16)(mv[md] * 8.0f);
}

// ---------------------------------------------------------------------------
// Flash attention: grid (NSEQ/64, nb*16).  Wave w owns q-rows q0+w*16..+16,
// online softmax in regs; P C->A layout via per-wave LDS (m120).
// Q/O alias in-place; blocks touch disjoint [rows][head-cols] regions.
__global__ __launch_bounds__(256) void attn_flash(const bf16* Q,
        const bf16* __restrict__ K, const bf16* __restrict__ Vt,
        const int* __restrict__ mask, bf16* O)
{
    __shared__ bf16  sK[64][72];
    __shared__ bf16  sV[64][72];
    __shared__ bf16  sP[4][16][72];
    __shared__ float sM[NKV];
    const int t = threadIdx.x, lane = t & 63, w = t >> 6;
    const int bh = blockIdx.y, b = bh >> 4, h = bh & 15;
    const int q0 = blockIdx.x * 64;
    const int sr = t >> 2, sc = (t & 3) * 16;
    const int qi = lane & 15, qq = lane >> 4;

    for (int j = t; j < NKV; j += 256)
        sM[j] = (j < NSEQ && mask[b * NSEQ + j] != 0) ? -3.0e38f : 0.0f;

    const size_t qbase = (size_t)(b * NSEQ + q0 + w * 16 + qi) * DMODEL
                       + h * 64 + qq * 8;
    bf16x8 qa0 = *(const bf16x8*)&Q[qbase];
    bf16x8 qa1 = *(const bf16x8*)&Q[qbase + 32];

    float m_i[4], l_i[4];
    f32x4 oacc[4] = {};
    for (int r = 0; r < 4; r++) { m_i[r] = -3.0e38f; l_i[r] = 0.f; }

    for (int jt = 0; jt < 17; jt++) {
        const int j0 = jt * 64;
        const bf16* kp = K + (size_t)(b * NKV + j0 + sr) * DMODEL + h * 64 + sc;
        *(bf16x8*)&sK[sr][sc]     = *(const bf16x8*)kp;
        *(bf16x8*)&sK[sr][sc + 8] = *(const bf16x8*)(kp + 8);
        const bf16* vp = Vt + ((size_t)bh * 64 + sr) * NKV + j0 + sc;
        *(bf16x8*)&sV[sr][sc]     = *(const bf16x8*)vp;
        *(bf16x8*)&sV[sr][sc + 8] = *(const bf16x8*)(vp + 8);
        __syncthreads();

        f32x4 s[4];
        for (int g = 0; g < 4; g++) {
            bf16x8 b0 = *(const bf16x8*)&sK[g * 16 + qi][qq * 8];
            bf16x8 b1 = *(const bf16x8*)&sK[g * 16 + qi][32 + qq * 8];
            f32x4 a = {};
            a = __builtin_amdgcn_mfma_f32_16x16x32_bf16(qa0, b0, a, 0, 0, 0);
            a = __builtin_amdgcn_mfma_f32_16x16x32_bf16(qa1, b1, a, 0, 0, 0);
            float msk = sM[j0 + g * 16 + qi];
            for (int r = 0; r < 4; r++) s[g][r] = a[r] * 0.125f + msk;
        }
        float alpha[4];
        for (int r = 0; r < 4; r++) {
            float rm = fmaxf(fmaxf(s[0][r], s[1][r]), fmaxf(s[2][r], s[3][r]));
            for (int o = 1; o < 16; o <<= 1) rm = fmaxf(rm, __shfl_xor(rm, o, 64));
            float mnew = fmaxf(m_i[r], rm);
            alpha[r] = __expf(m_i[r] - mnew);
            m_i[r] = mnew;
            float rs = 0.f;
            for (int g = 0; g < 4; g++) {
                float p = __expf(s[g][r] - mnew);
                s[g][r] = p;
                rs += p;
            }
            for (int o = 1; o < 16; o <<= 1) rs += __shfl_xor(rs, o, 64);
            l_i[r] = l_i[r] * alpha[r] + rs;
        }
        for (int g = 0; g < 4; g++)
            for (int r = 0; r < 4; r++) {
                sP[w][qq * 4 + r][g * 16 + qi] = (bf16)s[g][r];
                oacc[g][r] *= alpha[r];
            }
        bf16x8 af0 = *(const bf16x8*)&sP[w][qi][qq * 8];
        bf16x8 af1 = *(const bf16x8*)&sP[w][qi][32 + qq * 8];
        for (int g = 0; g < 4; g++) {
            bf16x8 v0 = *(const bf16x8*)&sV[g * 16 + qi][qq * 8];
            bf16x8 v1 = *(const bf16x8*)&sV[g * 16 + qi][32 + qq * 8];
            oacc[g] = __builtin_amdgcn_mfma_f32_16x16x32_bf16(af0, v0, oacc[g], 0, 0, 0);
            oacc[g] = __builtin_amdgcn_mfma_f32_16x16x32_bf16(af1, v1, oacc[g], 0, 0, 0);
        }
        __syncthreads();
    }
    for (int g = 0; g < 4; g++)
        for (int r = 0; r < 4; r++) {
            int row = q0 + w * 16 + qq * 4 + r;
            int col = h * 64 + g * 16 + qi;
            O[(size_t)(b * NSEQ + row) * DMODEL + col] = (bf16)(oacc[g][r] / l_i[r]);
        }
}

// ---------------------------------------------------------------------------
__global__ __launch_bounds__(256) void residual_ln(const float* __restrict__ X,
        const bf16* __restrict__ Y, const float* __restrict__ gamma,
        const float* __restrict__ beta, float* __restrict__ out)
{
    __shared__ float red[8];
    int row = blockIdx.x, t = threadIdx.x;
    size_t base = (size_t)row * DMODEL + t * 4;
    f32x4  xv = *(const f32x4*)&X[base];
    bf16x4 yv = *(const bf16x4*)&Y[base];
    float s[4], sum = 0.f, sq = 0.f;
    for (int i = 0; i < 4; i++) {
        s[i] = xv[i] + (float)yv[i];
        sum += s[i]; sq += s[i] * s[i];
    }
    for (int o = 32; o; o >>= 1) { sum += __shfl_xor(sum, o, 64); sq += __shfl_xor(sq, o, 64); }
    if ((t & 63) == 0) { red[t >> 6] = sum; red[4 + (t >> 6)] = sq; }
    __syncthreads();
    sum = red[0] + red[1] + red[2] + red[3];
    sq  = red[4] + red[5] + red[6] + red[7];
    float mean = sum * (1.0f / DMODEL);
    float var  = sq  * (1.0f / DMODEL) - mean * mean;
    float rstd = rsqrtf(var + 1e-5f);
    f32x4 gv = *(const f32x4*)&gamma[t * 4];
    f32x4 bv = *(const f32x4*)&beta[t * 4];
    f32x4 ov;
    for (int i = 0; i < 4; i++)
        ov[i] = (s[i] - mean) * rstd * gv[i] + bv[i];
    *(f32x4*)&out[base] = ov;
}

// ---------------------------------------------------------------------------
extern "C" void kernel_launch(void* const* d_in, const int* in_sizes, int n_in,
                              void* d_out, int out_size, void* d_ws, size_t ws_size,
                              hipStream_t stream)
{
    const float* queries = (const float*)d_in[0];
    const float* keys    = (const float*)d_in[1];
    const float* values  = (const float*)d_in[2];
    const int*   amask   = (const int*)d_in[3];
    const float* Wq = (const float*)d_in[4];  const float* bq = (const float*)d_in[5];
    const float* Wk = (const float*)d_in[6];  const float* bk = (const float*)d_in[7];
    const float* Wv = (const float*)d_in[8];  const float* bv = (const float*)d_in[9];
    const float* Wo = (const float*)d_in[10]; const float* bo = (const float*)d_in[11];
    const float* mk = (const float*)d_in[12]; const float* mv = (const float*)d_in[13];
    const float* gamma = (const float*)d_in[14]; const float* beta = (const float*)d_in[15];
    float* out = (float*)d_out;

    bf16* Qb = (bf16*)(out + (size_t)2 * 1024 * 1024);   // d_out upper 8 MB
    const size_t SB  = (size_t)NSEQ * DMODEL;
    const size_t KVB = (size_t)NKV * DMODEL;
    dim3 gb(256);

    if (ws_size >= (size_t)2 * 4 * KVB * sizeof(bf16)) {
        // ---------- fully batched path (ws >= 17,825,792 B) ----------
        bf16* Kb = (bf16*)d_ws;            // [4][1088][1024]
        bf16* Vt = Kb + 4 * KVB;           // [4*16*64][1088]
        bf16* PR = Kb;                     // [4096][1024] aliases dead Kb

        GemmArgs gq{queries, Wq, bq, Qb, (int)SB,  0};
        GemmArgs gk{keys,    Wk, bk, Kb, (int)KVB, 0};
        GemmArgs gv{values,  Wv, bv, Vt, 0,        1};
        gemm128<false><<<dim3(8, 32, 3), gb, 0, stream>>>(gq, gk, gv);
        fill_mem<<<dim3(1024), gb, 0, stream>>>(mk, mv, Kb, Vt);
        attn_flash<<<dim3(16, 64), gb, 0, stream>>>(Qb, Kb, Vt, amask, Qb);
        GemmArgs go{Qb, Wo, bo, PR, (int)SB, 0};
        gemm128<true><<<dim3(8, 32, 1), gb, 0, stream>>>(go, go, go);
        residual_ln<<<dim3(4096), gb, 0, stream>>>(queries, PR, gamma, beta, out);
    } else {
        // ---------- per-batch fallback (ws >= 4,456,448 B) ----------
        bf16* Kb = (bf16*)d_ws;            // [1088][1024]
        bf16* Vt = Kb + KVB;               // [16*64][1088]
        bf16* PR = Kb;

        GemmArgs gq{queries, Wq, bq, Qb, (int)SB, 0};
        gemm128<false><<<dim3(8, 32, 1), gb, 0, stream>>>(gq, gq, gq);
        for (int b = 0; b < 4; b++) {
            GemmArgs gk{keys   + b * SB, Wk, bk, Kb, 0, 0};
            GemmArgs gv{values + b * SB, Wv, bv, Vt, 0, 1};
            gemm128<false><<<dim3(8, 8, 2), gb, 0, stream>>>(gk, gv, gv);
            fill_mem<<<dim3(256), gb, 0, stream>>>(mk, mv, Kb, Vt);
            attn_flash<<<dim3(16, 16), gb, 0, stream>>>(Qb + b * SB, Kb, Vt,
                                                        amask + b * NSEQ, Qb + b * SB);
            GemmArgs go{Qb + b * SB, Wo, bo, PR, 0, 0};
            gemm128<true><<<dim3(8, 8, 1), gb, 0, stream>>>(go, go, go);
            residual_ln<<<dim3(1024), gb, 0, stream>>>(queries + b * SB, PR,
                                                       gamma, beta, out + b * SB);
        }
    }
}

// Round 9
// 296.183 us; speedup vs baseline: 2.5631x; 1.0202x over previous
//
#include <hip/hip_runtime.h>

// MultiHeadAttention with memory tokens + residual + LayerNorm.
// Inputs f32 (mask int32), OUTPUT f32.  B=4, N=1024, D=1024, H=16, DK=64,
// M=64, NKV=1088.  Intermediates bf16 (MFMA), f32 accumulation.
//
// R9: register double-buffer prefetch in gemm128 + attn_flash (hide global
// latency behind MFMA).  d_out upper half doubles as Qb [4][1024][1024] bf16.

typedef __bf16 bf16;
typedef __bf16 bf16x8 __attribute__((ext_vector_type(8)));
typedef __bf16 bf16x4 __attribute__((ext_vector_type(4)));
typedef float  f32x4  __attribute__((ext_vector_type(4)));

#define NSEQ 1024
#define NKV  1088
#define DMODEL 1024

struct GemmArgs {
    const void* A;        // [M][1024] f32 (or bf16 if ABF)
    const float* W;       // [1024][1024] f32
    const float* bias;    // [1024] f32
    bf16* C;
    int osK;              // batch stride for multi-batch row remap (vt=0)
    int vt;               // 1: V-transposed epilogue
};

// ---------------------------------------------------------------------------
// C = A @ W.T + bias.  128x128 tile, BK=32, 4 waves (2x2), 4x4 16x16 frags,
// register-dbuf prefetch of the next K-tile.  grid (N/128, M/128, nz).
template<bool ABF>
__global__ __launch_bounds__(256, 2) void gemm128(GemmArgs g0, GemmArgs g1, GemmArgs g2)
{
    const GemmArgs g = (blockIdx.z == 0) ? g0 : (blockIdx.z == 1) ? g1 : g2;
    __shared__ bf16 As[128][44];
    __shared__ bf16 Bs[128][44];
    const int t = threadIdx.x;
    const int lane = t & 63, w = t >> 6;
    const int qi = lane & 15, qq = lane >> 4;
    const int wrow = (w >> 1) * 64, wcol = (w & 1) * 64;
    const int bm = blockIdx.y * 128, bn = blockIdx.x * 128;
    const int sr = t >> 1, sc = (t & 1) * 16;   // staging: 2 thr/row, 16 elems

    f32x4 acc[4][4] = {};

    // prefetch registers
    f32x4 pa[4];      // A tile (f32 path)
    bf16x8 pab[2];    // A tile (bf16 path)
    f32x4 pw[4];      // W tile (always f32)

    const float* Wp = g.W + (size_t)(bn + sr) * DMODEL + sc;
    const float* Af = (const float*)g.A + (size_t)(bm + sr) * DMODEL + sc;
    const bf16*  Ab = (const bf16*)g.A + (size_t)(bm + sr) * DMODEL + sc;

#define LOAD_TILES(kt)                                                        \
    do {                                                                      \
        if (ABF) {                                                            \
            pab[0] = *(const bf16x8*)(Ab + (kt));                             \
            pab[1] = *(const bf16x8*)(Ab + (kt) + 8);                         \
        } else {                                                              \
            pa[0] = *(const f32x4*)(Af + (kt));                               \
            pa[1] = *(const f32x4*)(Af + (kt) + 4);                           \
            pa[2] = *(const f32x4*)(Af + (kt) + 8);                           \
            pa[3] = *(const f32x4*)(Af + (kt) + 12);                          \
        }                                                                     \
        pw[0] = *(const f32x4*)(Wp + (kt));                                   \
        pw[1] = *(const f32x4*)(Wp + (kt) + 4);                               \
        pw[2] = *(const f32x4*)(Wp + (kt) + 8);                               \
        pw[3] = *(const f32x4*)(Wp + (kt) + 12);                              \
    } while (0)

#define STORE_TILES()                                                         \
    do {                                                                      \
        if (ABF) {                                                            \
            *(bf16x8*)&As[sr][sc]     = pab[0];                               \
            *(bf16x8*)&As[sr][sc + 8] = pab[1];                               \
        } else {                                                              \
            bf16x8 v0, v1;                                                    \
            for (int i = 0; i < 4; i++) {                                     \
                v0[i] = (bf16)pa[0][i]; v0[4 + i] = (bf16)pa[1][i];           \
                v1[i] = (bf16)pa[2][i]; v1[4 + i] = (bf16)pa[3][i];           \
            }                                                                 \
            *(bf16x8*)&As[sr][sc]     = v0;                                   \
            *(bf16x8*)&As[sr][sc + 8] = v1;                                   \
        }                                                                     \
        {                                                                     \
            bf16x8 u0, u1;                                                    \
            for (int i = 0; i < 4; i++) {                                     \
                u0[i] = (bf16)pw[0][i]; u0[4 + i] = (bf16)pw[1][i];           \
                u1[i] = (bf16)pw[2][i]; u1[4 + i] = (bf16)pw[3][i];           \
            }                                                                 \
            *(bf16x8*)&Bs[sr][sc]     = u0;                                   \
            *(bf16x8*)&Bs[sr][sc + 8] = u1;                                   \
        }                                                                     \
    } while (0)

    LOAD_TILES(0);
    STORE_TILES();
    __syncthreads();

    for (int kt = 0; kt < DMODEL; kt += 32) {
        const bool more = (kt + 32) < DMODEL;
        if (more) LOAD_TILES(kt + 32);     // async: waitcnt lands in STORE
        bf16x8 a[4], b[4];
        for (int i = 0; i < 4; i++)
            a[i] = *(const bf16x8*)&As[wrow + i * 16 + qi][qq * 8];
        for (int j = 0; j < 4; j++)
            b[j] = *(const bf16x8*)&Bs[wcol + j * 16 + qi][qq * 8];
        for (int i = 0; i < 4; i++)
            for (int j = 0; j < 4; j++)
                acc[i][j] = __builtin_amdgcn_mfma_f32_16x16x32_bf16(a[i], b[j], acc[i][j], 0, 0, 0);
        if (more) {
            __syncthreads();
            STORE_TILES();
            __syncthreads();
        }
    }
#undef LOAD_TILES
#undef STORE_TILES

    // epilogue; C/D layout row=qq*4+r, col=qi  [m89-verified]
    for (int i = 0; i < 4; i++)
        for (int j = 0; j < 4; j++) {
            int row0 = bm + wrow + i * 16 + qq * 4;
            int col  = bn + wcol + j * 16 + qi;
            float bcol = g.bias[col];
            if (g.vt) {
                bf16x4 v;
                for (int r = 0; r < 4; r++) v[r] = (bf16)(acc[i][j][r] + bcol);
                size_t off = ((size_t)((row0 >> 10) * 16 + (col >> 6)) * 64 + (col & 63))
                           * NKV + (row0 & 1023);
                *(bf16x4*)&g.C[off] = v;
            } else {
                for (int r = 0; r < 4; r++) {
                    int row = row0 + r;
                    size_t off = (size_t)(row >> 10) * g.osK
                               + (size_t)(row & 1023) * DMODEL + col;
                    g.C[off] = (bf16)(acc[i][j][r] + bcol);
                }
            }
        }
}

// ---------------------------------------------------------------------------
__global__ void fill_mem(const float* __restrict__ mk, const float* __restrict__ mv,
                         bf16* __restrict__ K, bf16* __restrict__ Vt)
{
    int i = blockIdx.x * 256 + threadIdx.x;
    int b = i >> 16, md = i & 65535;
    int m = md >> 10, dcol = md & 1023;
    K[(size_t)b * (NKV * DMODEL) + (size_t)(NSEQ + m) * DMODEL + dcol]
        = (bf16)(mk[md] * 8.0f);
    Vt[((size_t)b * 1024 + dcol) * NKV + NSEQ + m] = (bf16)(mv[md] * 8.0f);
}

// ---------------------------------------------------------------------------
// Flash attention with register-dbuf K/V prefetch.  grid (NSEQ/64, nb*16).
// Wave w owns q-rows q0+w*16..+16; online softmax in regs; P C->A layout via
// per-wave LDS (m120).  Q pre-scaled by 1/sqrt(DK) (exact in bf16).
__global__ __launch_bounds__(256) void attn_flash(const bf16* Q,
        const bf16* __restrict__ K, const bf16* __restrict__ Vt,
        const int* __restrict__ mask, bf16* O)
{
    __shared__ bf16  sK[64][72];
    __shared__ bf16  sV[64][72];
    __shared__ bf16  sP[4][16][72];
    __shared__ float sM[NKV];
    const int t = threadIdx.x, lane = t & 63, w = t >> 6;
    const int bh = blockIdx.y, b = bh >> 4, h = bh & 15;
    const int q0 = blockIdx.x * 64;
    const int sr = t >> 2, sc = (t & 3) * 16;
    const int qi = lane & 15, qq = lane >> 4;

    for (int j = t; j < NKV; j += 256)
        sM[j] = (j < NSEQ && mask[b * NSEQ + j] != 0) ? -3.0e38f : 0.0f;

    // Q a-frags, pre-scaled by 0.125 (power of 2: exact in bf16)
    const size_t qbase = (size_t)(b * NSEQ + q0 + w * 16 + qi) * DMODEL
                       + h * 64 + qq * 8;
    bf16x8 qa0 = *(const bf16x8*)&Q[qbase];
    bf16x8 qa1 = *(const bf16x8*)&Q[qbase + 32];
    for (int i = 0; i < 8; i++) {
        qa0[i] = (bf16)((float)qa0[i] * 0.125f);
        qa1[i] = (bf16)((float)qa1[i] * 0.125f);
    }

    const bf16* kbase = K + (size_t)(b * NKV + sr) * DMODEL + h * 64 + sc;
    const bf16* vbase = Vt + ((size_t)bh * 64 + sr) * NKV + sc;

    bf16x8 pk0, pk1, pv0, pv1;
#define LOAD_KV(jt)                                                           \
    do {                                                                      \
        const bf16* kp = kbase + (size_t)(jt) * 64 * DMODEL;                  \
        pk0 = *(const bf16x8*)kp;                                             \
        pk1 = *(const bf16x8*)(kp + 8);                                       \
        const bf16* vp = vbase + (jt) * 64;                                   \
        pv0 = *(const bf16x8*)vp;                                             \
        pv1 = *(const bf16x8*)(vp + 8);                                       \
    } while (0)
#define STORE_KV()                                                            \
    do {                                                                      \
        *(bf16x8*)&sK[sr][sc]     = pk0;                                      \
        *(bf16x8*)&sK[sr][sc + 8] = pk1;                                      \
        *(bf16x8*)&sV[sr][sc]     = pv0;                                      \
        *(bf16x8*)&sV[sr][sc + 8] = pv1;                                      \
    } while (0)

    LOAD_KV(0);
    STORE_KV();

    float m_i[4], l_i[4];
    f32x4 oacc[4] = {};
    for (int r = 0; r < 4; r++) { m_i[r] = -3.0e38f; l_i[r] = 0.f; }

    for (int jt = 0; jt < 17; jt++) {
        const int j0 = jt * 64;
        __syncthreads();                       // staged tile visible
        const bool more = jt < 16;
        if (more) LOAD_KV(jt + 1);             // prefetch; waitcnt at STORE_KV

        f32x4 s[4];
        for (int g = 0; g < 4; g++) {
            bf16x8 b0 = *(const bf16x8*)&sK[g * 16 + qi][qq * 8];
            bf16x8 b1 = *(const bf16x8*)&sK[g * 16 + qi][32 + qq * 8];
            f32x4 a = {};
            a = __builtin_amdgcn_mfma_f32_16x16x32_bf16(qa0, b0, a, 0, 0, 0);
            a = __builtin_amdgcn_mfma_f32_16x16x32_bf16(qa1, b1, a, 0, 0, 0);
            float msk = sM[j0 + g * 16 + qi];
            for (int r = 0; r < 4; r++) s[g][r] = a[r] + msk;
        }
        float alpha[4];
        for (int r = 0; r < 4; r++) {
            float rm = fmaxf(fmaxf(s[0][r], s[1][r]), fmaxf(s[2][r], s[3][r]));
            for (int o = 1; o < 16; o <<= 1) rm = fmaxf(rm, __shfl_xor(rm, o, 64));
            float mnew = fmaxf(m_i[r], rm);
            alpha[r] = __expf(m_i[r] - mnew);
            m_i[r] = mnew;
            float rs = 0.f;
            for (int g = 0; g < 4; g++) {
                float p = __expf(s[g][r] - mnew);
                s[g][r] = p;
                rs += p;
            }
            for (int o = 1; o < 16; o <<= 1) rs += __shfl_xor(rs, o, 64);
            l_i[r] = l_i[r] * alpha[r] + rs;
        }
        for (int g = 0; g < 4; g++)
            for (int r = 0; r < 4; r++) {
                sP[w][qq * 4 + r][g * 16 + qi] = (bf16)s[g][r];
                oacc[g][r] *= alpha[r];
            }
        bf16x8 af0 = *(const bf16x8*)&sP[w][qi][qq * 8];
        bf16x8 af1 = *(const bf16x8*)&sP[w][qi][32 + qq * 8];
        for (int g = 0; g < 4; g++) {
            bf16x8 v0 = *(const bf16x8*)&sV[g * 16 + qi][qq * 8];
            bf16x8 v1 = *(const bf16x8*)&sV[g * 16 + qi][32 + qq * 8];
            oacc[g] = __builtin_amdgcn_mfma_f32_16x16x32_bf16(af0, v0, oacc[g], 0, 0, 0);
            oacc[g] = __builtin_amdgcn_mfma_f32_16x16x32_bf16(af1, v1, oacc[g], 0, 0, 0);
        }
        __syncthreads();                       // done reading sK/sV
        if (more) STORE_KV();
    }
#undef LOAD_KV
#undef STORE_KV

    float inv[4];
    for (int r = 0; r < 4; r++) inv[r] = 1.0f / l_i[r];
    for (int g = 0; g < 4; g++)
        for (int r = 0; r < 4; r++) {
            int row = q0 + w * 16 + qq * 4 + r;
            int col = h * 64 + g * 16 + qi;
            O[(size_t)(b * NSEQ + row) * DMODEL + col] = (bf16)(oacc[g][r] * inv[r]);
        }
}

// ---------------------------------------------------------------------------
__global__ __launch_bounds__(256) void residual_ln(const float* __restrict__ X,
        const bf16* __restrict__ Y, const float* __restrict__ gamma,
        const float* __restrict__ beta, float* __restrict__ out)
{
    __shared__ float red[8];
    int row = blockIdx.x, t = threadIdx.x;
    size_t base = (size_t)row * DMODEL + t * 4;
    f32x4  xv = *(const f32x4*)&X[base];
    bf16x4 yv = *(const bf16x4*)&Y[base];
    float s[4], sum = 0.f, sq = 0.f;
    for (int i = 0; i < 4; i++) {
        s[i] = xv[i] + (float)yv[i];
        sum += s[i]; sq += s[i] * s[i];
    }
    for (int o = 32; o; o >>= 1) { sum += __shfl_xor(sum, o, 64); sq += __shfl_xor(sq, o, 64); }
    if ((t & 63) == 0) { red[t >> 6] = sum; red[4 + (t >> 6)] = sq; }
    __syncthreads();
    sum = red[0] + red[1] + red[2] + red[3];
    sq  = red[4] + red[5] + red[6] + red[7];
    float mean = sum * (1.0f / DMODEL);
    float var  = sq  * (1.0f / DMODEL) - mean * mean;
    float rstd = rsqrtf(var + 1e-5f);
    f32x4 gv = *(const f32x4*)&gamma[t * 4];
    f32x4 bv = *(const f32x4*)&beta[t * 4];
    f32x4 ov;
    for (int i = 0; i < 4; i++)
        ov[i] = (s[i] - mean) * rstd * gv[i] + bv[i];
    *(f32x4*)&out[base] = ov;
}

// ---------------------------------------------------------------------------
extern "C" void kernel_launch(void* const* d_in, const int* in_sizes, int n_in,
                              void* d_out, int out_size, void* d_ws, size_t ws_size,
                              hipStream_t stream)
{
    const float* queries = (const float*)d_in[0];
    const float* keys    = (const float*)d_in[1];
    const float* values  = (const float*)d_in[2];
    const int*   amask   = (const int*)d_in[3];
    const float* Wq = (const float*)d_in[4];  const float* bq = (const float*)d_in[5];
    const float* Wk = (const float*)d_in[6];  const float* bk = (const float*)d_in[7];
    const float* Wv = (const float*)d_in[8];  const float* bv = (const float*)d_in[9];
    const float* Wo = (const float*)d_in[10]; const float* bo = (const float*)d_in[11];
    const float* mk = (const float*)d_in[12]; const float* mv = (const float*)d_in[13];
    const float* gamma = (const float*)d_in[14]; const float* beta = (const float*)d_in[15];
    float* out = (float*)d_out;

    bf16* Qb = (bf16*)(out + (size_t)2 * 1024 * 1024);   // d_out upper 8 MB
    const size_t SB  = (size_t)NSEQ * DMODEL;
    const size_t KVB = (size_t)NKV * DMODEL;
    dim3 gb(256);

    if (ws_size >= (size_t)2 * 4 * KVB * sizeof(bf16)) {
        // ---------- fully batched path (ws >= 17,825,792 B) ----------
        bf16* Kb = (bf16*)d_ws;            // [4][1088][1024]
        bf16* Vt = Kb + 4 * KVB;           // [4*16*64][1088]
        bf16* PR = Kb;                     // [4096][1024] aliases dead Kb

        GemmArgs gq{queries, Wq, bq, Qb, (int)SB,  0};
        GemmArgs gk{keys,    Wk, bk, Kb, (int)KVB, 0};
        GemmArgs gv{values,  Wv, bv, Vt, 0,        1};
        gemm128<false><<<dim3(8, 32, 3), gb, 0, stream>>>(gq, gk, gv);
        fill_mem<<<dim3(1024), gb, 0, stream>>>(mk, mv, Kb, Vt);
        attn_flash<<<dim3(16, 64), gb, 0, stream>>>(Qb, Kb, Vt, amask, Qb);
        GemmArgs go{Qb, Wo, bo, PR, (int)SB, 0};
        gemm128<true><<<dim3(8, 32, 1), gb, 0, stream>>>(go, go, go);
        residual_ln<<<dim3(4096), gb, 0, stream>>>(queries, PR, gamma, beta, out);
    } else {
        // ---------- per-batch fallback (ws >= 4,456,448 B) ----------
        bf16* Kb = (bf16*)d_ws;            // [1088][1024]
        bf16* Vt = Kb + KVB;               // [16*64][1088]
        bf16* PR = Kb;

        GemmArgs gq{queries, Wq, bq, Qb, (int)SB, 0};
        gemm128<false><<<dim3(8, 32, 1), gb, 0, stream>>>(gq, gq, gq);
        for (int b = 0; b < 4; b++) {
            GemmArgs gk{keys   + b * SB, Wk, bk, Kb, 0, 0};
            GemmArgs gv{values + b * SB, Wv, bv, Vt, 0, 1};
            gemm128<false><<<dim3(8, 8, 2), gb, 0, stream>>>(gk, gv, gv);
            fill_mem<<<dim3(256), gb, 0, stream>>>(mk, mv, Kb, Vt);
            attn_flash<<<dim3(16, 16), gb, 0, stream>>>(Qb + b * SB, Kb, Vt,
                                                        amask + b * NSEQ, Qb + b * SB);
            GemmArgs go{Qb + b * SB, Wo, bo, PR, 0, 0};
            gemm128<true><<<dim3(8, 8, 1), gb, 0, stream>>>(go, go, go);
            residual_ln<<<dim3(1024), gb, 0, stream>>>(queries + b * SB, PR,
                                                       gamma, beta, out + b * SB);
        }
    }
}